// Round 8
// baseline (220.543 us; speedup 1.0000x reference)
//
#include <hip/hip_runtime.h>

typedef float    f32x4 __attribute__((ext_vector_type(4)));
typedef _Float16 f16x2 __attribute__((ext_vector_type(2)));
typedef _Float16 f16x4 __attribute__((ext_vector_type(4)));
typedef _Float16 f16x8 __attribute__((ext_vector_type(8)));
typedef int      i32x4 __attribute__((ext_vector_type(4)));

namespace {
constexpr int B_ = 2, L_ = 2048, S_ = 2048, H_ = 16, E_ = 64;
constexpr int MBLK = 64;         // q rows per block (4 waves x 16)
constexpr int NT = 64;           // s-tile width
constexpr int NTILES = S_ / NT;  // 32
constexpr int KPAD = 72;         // LDS row stride (halves): 144 B, 16B-aligned rows

#define SCALE2f 0.1803368801111204f /* 0.125 * log2(e) */
#define MBIAS2f -1.8033688e8f       /* -1e9 * 0.125 * log2(e): exp2 -> exactly 0 */

__device__ __forceinline__ f16x2 cvt2(float a, float b) {  // 2x f32 -> f16x2 (1 instr)
  return __builtin_bit_cast(f16x2, __builtin_amdgcn_cvt_pkrtz(a, b));
}
__device__ __forceinline__ int pkh(float a, float b) {
  return __builtin_bit_cast(int, __builtin_amdgcn_cvt_pkrtz(a, b));
}
union H8 { f16x8 v; i32x4 i; };
union H4 { f16x4 v; f16x2 h[2]; };
}  // namespace

// ---- pre-pass: mask fp32 [B,1,L,S] -> 1 bit/element, u64 per (row, s-tile)
extern "C" __global__ __launch_bounds__(256)
void maskpack_kernel(const float* __restrict__ Mg, unsigned long long* __restrict__ Wb) {
  const int w    = (int)((blockIdx.x * 256 + threadIdx.x) >> 6);  // row id [0, B*L)
  const int lane = threadIdx.x & 63;
  const float* src = Mg + (size_t)w * 2048 + lane;
  unsigned long long* dst = Wb + (size_t)w * 32;
#pragma unroll 8
  for (int j = 0; j < 32; ++j) {
    const unsigned long long bits = __ballot(src[j * 64] > 0.5f);
    if (lane == 0) dst[j] = bits;
  }
}

extern "C" __global__ __launch_bounds__(256, 4)
void fattn_kernel(const float* __restrict__ Qg, const float* __restrict__ Kg,
                  const float* __restrict__ Vg, const unsigned long long* __restrict__ Wb,
                  float* __restrict__ Og) {
  __shared__ __align__(16) _Float16 Ks[2][NT][KPAD];  // K tile [s][e], double-buffered
  __shared__ __align__(16) _Float16 Vt[2][E_][KPAD];  // V^T tile [e][s], double-buffered

  const int tid  = threadIdx.x;
  const int wv   = tid >> 6;
  const int lane = tid & 63;
  const int qd   = lane >> 4;
  const int cl   = lane & 15;

  // XCD-locality: bid%8 == bh%8 -> all 32 q-blocks of one (b,h) on one XCD
  const int bid = blockIdx.x;
  const int qb  = bid >> 5;
  const int bh  = bid & 31;
  const int h   = bh & (H_ - 1);
  const int b   = bh >> 4;

  const int l0 = qb * MBLK + wv * 16;  // wave owns 16 q rows

  // ---- Q fragments (B-operand of S^T = K Q^T), f16: B[n=q=cl][k=e=qd*8+j(+32kb)]
  f16x8 qf[2];
  {
    const float* qp = Qg + ((((size_t)b * L_ + (l0 + cl)) * H_ + h) << 6);
#pragma unroll
    for (int kb = 0; kb < 2; ++kb) {
      const int e0 = qd * 8 + kb * 32;
      f32x4 x = *(const f32x4*)(qp + e0);
      f32x4 y = *(const f32x4*)(qp + e0 + 4);
      H8 u;
      u.i = (i32x4){pkh(x[0], x[1]), pkh(x[2], x[3]), pkh(y[0], y[1]), pkh(y[2], y[3])};
      qf[kb] = u.v;
    }
  }

  // ---- staging roles (256 threads)
  const int krow = tid >> 2;           // K: 64 rows x 4 thr x 16 floats
  const int kc0  = (tid & 3) << 4;
  const int vcol = tid & 31;           // V: s-pair index (s = 2*vcol, 2*vcol+1)
  const int ve0  = (tid >> 5) << 3;    // 8 e-rows per thread group

  const float* kptr  = Kg + ((((size_t)b * S_ + krow) * H_ + h) << 6) + kc0;
  const float* vptrA = Vg + ((((size_t)b * S_ + 2 * vcol) * H_ + h) << 6) + ve0;
  const float* vptrB = vptrA + (H_ << 6);  // next s row
  const size_t tstep = (size_t)NT * H_ * E_;

  const unsigned long long* wbp = Wb + (((size_t)b * L_ + (l0 + cl)) << 5);

  f32x4 kr[4], va[2], vb[2];
#pragma unroll
  for (int i = 0; i < 4; ++i) kr[i] = *(const f32x4*)(kptr + i * 4);
  va[0] = *(const f32x4*)(vptrA + 0); va[1] = *(const f32x4*)(vptrA + 4);
  vb[0] = *(const f32x4*)(vptrB + 0); vb[1] = *(const f32x4*)(vptrB + 4);

  const f32x4 zero4 = {0.f, 0.f, 0.f, 0.f};
  f32x4 acc[4];  // D[m=q][n=e]: q = qd*4 + r, e = et*16 + cl
#pragma unroll
  for (int et = 0; et < 4; ++et) acc[et] = zero4;
  f32x4 rs4 = zero4;

  // ---- stage tile 0 into buffer 0
  {
    i32x4 w0 = {pkh(kr[0][0], kr[0][1]), pkh(kr[0][2], kr[0][3]),
                pkh(kr[1][0], kr[1][1]), pkh(kr[1][2], kr[1][3])};
    i32x4 w1 = {pkh(kr[2][0], kr[2][1]), pkh(kr[2][2], kr[2][3]),
                pkh(kr[3][0], kr[3][1]), pkh(kr[3][2], kr[3][3])};
    *(i32x4*)&Ks[0][krow][kc0]     = w0;
    *(i32x4*)&Ks[0][krow][kc0 + 8] = w1;
#pragma unroll
    for (int j = 0; j < 4; ++j) {
      *(f16x2*)&Vt[0][ve0 + j][2 * vcol]     = cvt2(va[0][j], vb[0][j]);
      *(f16x2*)&Vt[0][ve0 + 4 + j][2 * vcol] = cvt2(va[1][j], vb[1][j]);
    }
  }
  // ---- load K/V for tile 1 into regs
#pragma unroll
  for (int i = 0; i < 4; ++i) kr[i] = *(const f32x4*)(kptr + tstep + i * 4);
  va[0] = *(const f32x4*)(vptrA + tstep + 0); va[1] = *(const f32x4*)(vptrA + tstep + 4);
  vb[0] = *(const f32x4*)(vptrB + tstep + 0); vb[1] = *(const f32x4*)(vptrB + tstep + 4);

  unsigned long long mwcur = wbp[0];

  for (int t = 0; t < NTILES; ++t) {
    const int cb = t & 1;
    __syncthreads();  // buf[cb] staged; buf[cb^1] readers (tile t-1) done

    unsigned long long mwnext = 0;
    if (t + 1 < NTILES) mwnext = wbp[t + 1];

    // ---- S^T = K Q^T  (A: Ks rows b128; B: Q regs). C: q=cl, s=nt*16+qd*4+r
    f32x4 sc[4];
#pragma unroll
    for (int nt = 0; nt < 4; ++nt) {
      const f16x8 a0 = *(const f16x8*)&Ks[cb][nt * 16 + cl][qd * 8];
      const f16x8 a1 = *(const f16x8*)&Ks[cb][nt * 16 + cl][qd * 8 + 32];
      f32x4 c = zero4;
      c = __builtin_amdgcn_mfma_f32_16x16x32_f16(a0, qf[0], c, 0, 0, 0);
      c = __builtin_amdgcn_mfma_f32_16x16x32_f16(a1, qf[1], c, 0, 0, 0);
      sc[nt] = c;
    }

    // ---- stage tile t+1 into buf[cb^1] (overlaps softmax/PV below)
    if (t + 1 < NTILES) {
      i32x4 w0 = {pkh(kr[0][0], kr[0][1]), pkh(kr[0][2], kr[0][3]),
                  pkh(kr[1][0], kr[1][1]), pkh(kr[1][2], kr[1][3])};
      i32x4 w1 = {pkh(kr[2][0], kr[2][1]), pkh(kr[2][2], kr[2][3]),
                  pkh(kr[3][0], kr[3][1]), pkh(kr[3][2], kr[3][3])};
      *(i32x4*)&Ks[cb ^ 1][krow][kc0]     = w0;
      *(i32x4*)&Ks[cb ^ 1][krow][kc0 + 8] = w1;
#pragma unroll
      for (int j = 0; j < 4; ++j) {
        *(f16x2*)&Vt[cb ^ 1][ve0 + j][2 * vcol]     = cvt2(va[0][j], vb[0][j]);
        *(f16x2*)&Vt[cb ^ 1][ve0 + 4 + j][2 * vcol] = cvt2(va[1][j], vb[1][j]);
      }
    }

    // ---- softmax numerator; P stays in REGISTERS as PV A-frags
    // (16x16x16 A-layout m=cl, k=qd*4+j == QK C-layout q=cl, s=qd*4+r)
    f16x4 pa[4];
    if (mwcur == ~0ull) {  // all-attend fast path
#pragma unroll
      for (int nt = 0; nt < 4; ++nt) {
        f32x4 p;
#pragma unroll
        for (int r = 0; r < 4; ++r)
          p[r] = __builtin_amdgcn_exp2f(sc[nt][r] * SCALE2f);
        rs4 += p;
        H4 u;
        u.h[0] = cvt2(p[0], p[1]);
        u.h[1] = cvt2(p[2], p[3]);
        pa[nt] = u.v;
      }
    } else {
      const unsigned lo = (unsigned)mwcur;
      const unsigned hi = (unsigned)(mwcur >> 32);
#pragma unroll
      for (int nt = 0; nt < 4; ++nt) {
        const unsigned sh = ((nt < 2) ? lo : hi) >> ((nt & 1) * 16 + qd * 4);
        f32x4 p;
#pragma unroll
        for (int r = 0; r < 4; ++r) {
          const float bias = (sh & (1u << r)) ? 0.f : MBIAS2f;
          p[r] = __builtin_amdgcn_exp2f(__builtin_fmaf(sc[nt][r], SCALE2f, bias));
        }
        rs4 += p;
        H4 u;
        u.h[0] = cvt2(p[0], p[1]);
        u.h[1] = cvt2(p[2], p[3]);
        pa[nt] = u.v;
      }
    }

    // ---- O += P V  (A: P regs; B: Vt rows b64). No LDS round-trip for P.
#pragma unroll
    for (int nt = 0; nt < 4; ++nt)
#pragma unroll
      for (int et = 0; et < 4; ++et) {
        const f16x4 bv = *(const f16x4*)&Vt[cb][et * 16 + cl][nt * 16 + qd * 4];
        acc[et] = __builtin_amdgcn_mfma_f32_16x16x16f16(pa[nt], bv, acc[et], 0, 0, 0);
      }

    // ---- issue global K/V loads for t+2
    if (t + 2 < NTILES) {
      const float* kp = kptr + (size_t)(t + 2) * tstep;
      const float* vpA = vptrA + (size_t)(t + 2) * tstep;
      const float* vpB = vptrB + (size_t)(t + 2) * tstep;
#pragma unroll
      for (int i = 0; i < 4; ++i) kr[i] = *(const f32x4*)(kp + i * 4);
      va[0] = *(const f32x4*)(vpA + 0); va[1] = *(const f32x4*)(vpA + 4);
      vb[0] = *(const f32x4*)(vpB + 0); vb[1] = *(const f32x4*)(vpB + 4);
    }
    mwcur = mwnext;
  }

  // ---- epilogue: row-sum reduce, broadcast inv per q-row, store
  {
    float v = rs4[0] + rs4[1] + rs4[2] + rs4[3];
    v += __shfl_xor(v, 16, 64);
    v += __shfl_xor(v, 32, 64);  // every lane: sum for q = cl
#pragma unroll
    for (int r = 0; r < 4; ++r) {
      const float invq = 1.0f / __shfl(v, qd * 4 + r, 64);  // sum for q = qd*4+r
      const int l = l0 + qd * 4 + r;
      float* op = Og + ((((size_t)b * H_ + h) * L_ + l) << 6) + cl;
#pragma unroll
      for (int et = 0; et < 4; ++et) op[et * 16] = acc[et][r] * invq;
    }
  }
}

extern "C" void kernel_launch(void* const* d_in, const int* in_sizes, int n_in,
                              void* d_out, int out_size, void* d_ws, size_t ws_size,
                              hipStream_t stream) {
  const float* Q = (const float*)d_in[0];
  const float* K = (const float*)d_in[1];
  const float* V = (const float*)d_in[2];
  const float* M = (const float*)d_in[3];
  float* O = (float*)d_out;
  unsigned long long* Wb = (unsigned long long*)d_ws;  // 2*2048*32*8 = 1 MiB

  hipLaunchKernelGGL(maskpack_kernel, dim3(B_ * L_ / 4), dim3(256), 0, stream, M, Wb);
  hipLaunchKernelGGL(fattn_kernel, dim3(B_ * H_ * (L_ / MBLK)), dim3(256), 0, stream,
                     Q, K, V, Wb, O);
}

// Round 10
// 179.296 us; speedup vs baseline: 1.2301x; 1.2301x over previous
//
#include <hip/hip_runtime.h>

typedef float    f32x4 __attribute__((ext_vector_type(4)));
typedef _Float16 f16x2 __attribute__((ext_vector_type(2)));
typedef _Float16 f16x4 __attribute__((ext_vector_type(4)));
typedef _Float16 f16x8 __attribute__((ext_vector_type(8)));
typedef int      i32x4 __attribute__((ext_vector_type(4)));

namespace {
constexpr int B_ = 2, L_ = 2048, S_ = 2048, H_ = 16, E_ = 64;
constexpr int MBLK = 128;        // q rows per block (4 waves x 32)
constexpr int NT = 128;          // s-cols per barrier interval (2 sub-phases of 64)
constexpr int NTILES = S_ / NT;  // 16
constexpr int KPAD = 72;         // Ks row stride (halves): 144 B, 16B-aligned
constexpr int VPAD = 136;        // Vt row stride (halves): 272 B, 16B-aligned

#define SCALE2f 0.1803368801111204f /* 0.125 * log2(e) */
#define MBIAS2f -1.8033688e8f       /* -1e9 * 0.125 * log2(e): exp2 -> exactly 0 */

__device__ __forceinline__ f16x2 cvt2(float a, float b) {
  return __builtin_bit_cast(f16x2, __builtin_amdgcn_cvt_pkrtz(a, b));
}
__device__ __forceinline__ int pkh(float a, float b) {
  return __builtin_bit_cast(int, __builtin_amdgcn_cvt_pkrtz(a, b));
}
union H8 { f16x8 v; i32x4 i; };
union H4 { f16x4 v; f16x2 h[2]; };
}  // namespace

// ---- pre-pass: mask fp32 [B,1,L,S] -> 1 bit/element, u64 per (row, 64-s-chunk)
extern "C" __global__ __launch_bounds__(256)
void maskpack_kernel(const float* __restrict__ Mg, unsigned long long* __restrict__ Wb) {
  const int w    = (int)((blockIdx.x * 256 + threadIdx.x) >> 6);  // row id [0, B*L)
  const int lane = threadIdx.x & 63;
  const float* src = Mg + (size_t)w * 2048 + lane;
  unsigned long long* dst = Wb + (size_t)w * 32;
#pragma unroll 8
  for (int j = 0; j < 32; ++j) {
    const unsigned long long bits = __ballot(src[j * 64] > 0.5f);
    if (lane == 0) dst[j] = bits;
  }
}

extern "C" __global__ __launch_bounds__(256, 2)
void fattn_kernel(const float* __restrict__ Qg, const float* __restrict__ Kg,
                  const float* __restrict__ Vg, const unsigned long long* __restrict__ Wb,
                  float* __restrict__ Og) {
  __shared__ __align__(16) _Float16 Ks[2][NT][KPAD];  // K tile [s][e]   36.9 KB
  __shared__ __align__(16) _Float16 Vt[2][E_][VPAD];  // V^T tile [e][s] 34.8 KB

  const int tid  = threadIdx.x;
  const int wv   = tid >> 6;
  const int lane = tid & 63;
  const int qd   = lane >> 4;
  const int cl   = lane & 15;

  // XCD-locality: bid%8 == bh%8 -> all 16 q-blocks of one (b,h) on one XCD
  const int bid = blockIdx.x;
  const int qb  = bid >> 5;
  const int bh  = bid & 31;
  const int h   = bh & (H_ - 1);
  const int b   = bh >> 4;

  const int l0 = qb * MBLK + wv * 32;

  // ---- Q fragments (B-operand of S^T = K Q^T), f16
  f16x8 qf[2][2];
#pragma unroll
  for (int mt = 0; mt < 2; ++mt) {
    const float* qp = Qg + ((((size_t)b * L_ + (l0 + mt * 16 + cl)) * H_ + h) << 6);
#pragma unroll
    for (int kb = 0; kb < 2; ++kb) {
      const int e0 = qd * 8 + kb * 32;
      f32x4 x = *(const f32x4*)(qp + e0);
      f32x4 y = *(const f32x4*)(qp + e0 + 4);
      H8 u;
      u.i = (i32x4){pkh(x[0], x[1]), pkh(x[2], x[3]), pkh(y[0], y[1]), pkh(y[2], y[3])};
      qf[mt][kb] = u.v;
    }
  }

  // ---- staging roles (256 threads, NT=128)
  const int krow = tid >> 2;           // K rows krow, krow+64; 4 thr x 16 floats each
  const int kc0  = (tid & 3) << 4;
  const int vcol = tid & 31;           // V s-pairs: 2vcol(+1), 2vcol+64(+65)
  const int ve0  = (tid >> 5) << 3;    // 8 e-rows per group

  const float* kptr = Kg + ((((size_t)b * S_ + krow) * H_ + h) << 6) + kc0;
  const float* vptr = Vg + ((((size_t)b * S_ + 2 * vcol) * H_ + h) << 6) + ve0;
  const size_t rs64 = (size_t)64 * H_ * E_;   // 64 s-rows
  const size_t rs1  = (size_t)H_ * E_;        // 1 s-row
  const size_t tstep = (size_t)NT * H_ * E_;  // one interval

  const unsigned long long* wbp = Wb + (((size_t)b * L_ + (l0 + cl)) << 5);

  f32x4 kr[8], vA0[2], vA1[2], vB0[2], vB1[2];
  auto load_kv = [&](int t) {
    const float* kp = kptr + (size_t)t * tstep;
    const float* vp = vptr + (size_t)t * tstep;
#pragma unroll
    for (int i = 0; i < 4; ++i) {
      kr[i]     = *(const f32x4*)(kp + i * 4);
      kr[i + 4] = *(const f32x4*)(kp + rs64 + i * 4);
    }
    vA0[0] = *(const f32x4*)(vp + 0);               vA0[1] = *(const f32x4*)(vp + 4);
    vA1[0] = *(const f32x4*)(vp + rs1 + 0);         vA1[1] = *(const f32x4*)(vp + rs1 + 4);
    vB0[0] = *(const f32x4*)(vp + rs64 + 0);        vB0[1] = *(const f32x4*)(vp + rs64 + 4);
    vB1[0] = *(const f32x4*)(vp + rs64 + rs1 + 0);  vB1[1] = *(const f32x4*)(vp + rs64 + rs1 + 4);
  };
  auto stage_kv = [&](int buf) {
#pragma unroll
    for (int hh = 0; hh < 2; ++hh) {
      i32x4 w0 = {pkh(kr[4*hh+0][0], kr[4*hh+0][1]), pkh(kr[4*hh+0][2], kr[4*hh+0][3]),
                  pkh(kr[4*hh+1][0], kr[4*hh+1][1]), pkh(kr[4*hh+1][2], kr[4*hh+1][3])};
      i32x4 w1 = {pkh(kr[4*hh+2][0], kr[4*hh+2][1]), pkh(kr[4*hh+2][2], kr[4*hh+2][3]),
                  pkh(kr[4*hh+3][0], kr[4*hh+3][1]), pkh(kr[4*hh+3][2], kr[4*hh+3][3])};
      *(i32x4*)&Ks[buf][krow + 64*hh][kc0]     = w0;
      *(i32x4*)&Ks[buf][krow + 64*hh][kc0 + 8] = w1;
    }
#pragma unroll
    for (int j = 0; j < 8; ++j) {
      *(f16x2*)&Vt[buf][ve0 + j][2 * vcol]      = cvt2(vA0[j>>2][j&3], vA1[j>>2][j&3]);
      *(f16x2*)&Vt[buf][ve0 + j][2 * vcol + 64] = cvt2(vB0[j>>2][j&3], vB1[j>>2][j&3]);
    }
  };

  const f32x4 zero4 = {0.f, 0.f, 0.f, 0.f};
  f32x4 acc[2][4];
#pragma unroll
  for (int mt = 0; mt < 2; ++mt)
#pragma unroll
    for (int et = 0; et < 4; ++et) acc[mt][et] = zero4;
  f32x4 rs4[2] = {zero4, zero4};

  load_kv(0);
  stage_kv(0);
  load_kv(1);
  unsigned long long mw[2] = {wbp[0], wbp[1]};

  for (int t = 0; t < NTILES; ++t) {
    const int cb = t & 1;
    __syncthreads();  // buf[cb] staged; buf[cb^1] readers (interval t-1) done

    unsigned long long mwn0 = 0, mwn1 = 0;
    if (t + 1 < NTILES) { mwn0 = wbp[2 * (t + 1)]; mwn1 = wbp[2 * (t + 1) + 1]; }

    // ---- stage interval t+1 from regs, then issue loads for t+2
    if (t + 1 < NTILES) stage_kv(cb ^ 1);
    if (t + 2 < NTILES) load_kv(t + 2);

    // ---- two independent 64-col sub-phases (no barrier between)
#pragma unroll
    for (int sub = 0; sub < 2; ++sub) {
      const int sb = sub * 64;
      // S^T = K Q^T
      f32x4 sc[4][2];
#pragma unroll
      for (int nt = 0; nt < 4; ++nt) {
        const f16x8 a0 = *(const f16x8*)&Ks[cb][sb + nt * 16 + cl][qd * 8];
        const f16x8 a1 = *(const f16x8*)&Ks[cb][sb + nt * 16 + cl][qd * 8 + 32];
#pragma unroll
        for (int mt = 0; mt < 2; ++mt) {
          f32x4 c = zero4;
          c = __builtin_amdgcn_mfma_f32_16x16x32_f16(a0, qf[mt][0], c, 0, 0, 0);
          c = __builtin_amdgcn_mfma_f32_16x16x32_f16(a1, qf[mt][1], c, 0, 0, 0);
          sc[nt][mt] = c;  // q = mt*16+cl, s = sb + nt*16 + qd*4 + r
        }
      }

      // softmax numerator; P stays in registers as PV A-frags
      f16x4 pa[2][4];
      const unsigned long long w = mw[sub];
      if (w == ~0ull) {
#pragma unroll
        for (int mt = 0; mt < 2; ++mt)
#pragma unroll
          for (int nt = 0; nt < 4; ++nt) {
            f32x4 p;
#pragma unroll
            for (int r = 0; r < 4; ++r)
              p[r] = __builtin_amdgcn_exp2f(sc[nt][mt][r] * SCALE2f);
            rs4[mt] += p;
            H4 u;
            u.h[0] = cvt2(p[0], p[1]);
            u.h[1] = cvt2(p[2], p[3]);
            pa[mt][nt] = u.v;
          }
      } else {
        const unsigned lo = (unsigned)w;
        const unsigned hi = (unsigned)(w >> 32);
#pragma unroll
        for (int mt = 0; mt < 2; ++mt)
#pragma unroll
          for (int nt = 0; nt < 4; ++nt) {
            const unsigned sh = ((nt < 2) ? lo : hi) >> ((nt & 1) * 16 + qd * 4);
            f32x4 p;
#pragma unroll
            for (int r = 0; r < 4; ++r) {
              const float bias = (sh & (1u << r)) ? 0.f : MBIAS2f;
              p[r] = __builtin_amdgcn_exp2f(__builtin_fmaf(sc[nt][mt][r], SCALE2f, bias));
            }
            rs4[mt] += p;
            H4 u;
            u.h[0] = cvt2(p[0], p[1]);
            u.h[1] = cvt2(p[2], p[3]);
            pa[mt][nt] = u.v;
          }
      }

      // O += P V
#pragma unroll
      for (int nt = 0; nt < 4; ++nt)
#pragma unroll
        for (int et = 0; et < 4; ++et) {
          const f16x4 bv = *(const f16x4*)&Vt[cb][et * 16 + cl][sb + nt * 16 + qd * 4];
          acc[0][et] = __builtin_amdgcn_mfma_f32_16x16x16f16(pa[0][nt], bv, acc[0][et], 0, 0, 0);
          acc[1][et] = __builtin_amdgcn_mfma_f32_16x16x16f16(pa[1][nt], bv, acc[1][et], 0, 0, 0);
        }
    }

    mw[0] = mwn0;
    mw[1] = mwn1;
  }

  // ---- epilogue: row-sum reduce, broadcast inv per q-row, store
#pragma unroll
  for (int mt = 0; mt < 2; ++mt) {
    float v = rs4[mt][0] + rs4[mt][1] + rs4[mt][2] + rs4[mt][3];
    v += __shfl_xor(v, 16, 64);
    v += __shfl_xor(v, 32, 64);  // every lane: sum for q = mt*16 + cl
#pragma unroll
    for (int r = 0; r < 4; ++r) {
      const float invq = 1.0f / __shfl(v, qd * 4 + r, 64);
      const int l = l0 + mt * 16 + qd * 4 + r;
      float* op = Og + ((((size_t)b * H_ + h) * L_ + l) << 6) + cl;
#pragma unroll
      for (int et = 0; et < 4; ++et) op[et * 16] = acc[mt][et][r] * invq;
    }
  }
}

extern "C" void kernel_launch(void* const* d_in, const int* in_sizes, int n_in,
                              void* d_out, int out_size, void* d_ws, size_t ws_size,
                              hipStream_t stream) {
  const float* Q = (const float*)d_in[0];
  const float* K = (const float*)d_in[1];
  const float* V = (const float*)d_in[2];
  const float* M = (const float*)d_in[3];
  float* O = (float*)d_out;
  unsigned long long* Wb = (unsigned long long*)d_ws;  // 1 MiB

  hipLaunchKernelGGL(maskpack_kernel, dim3(B_ * L_ / 4), dim3(256), 0, stream, M, Wb);
  hipLaunchKernelGGL(fattn_kernel, dim3(B_ * H_ * (L_ / MBLK)), dim3(256), 0, stream,
                     Q, K, V, Wb, O);
}

// Round 11
// 175.802 us; speedup vs baseline: 1.2545x; 1.0199x over previous
//
#include <hip/hip_runtime.h>

typedef float    f32x4 __attribute__((ext_vector_type(4)));
typedef _Float16 f16x2 __attribute__((ext_vector_type(2)));
typedef _Float16 f16x4 __attribute__((ext_vector_type(4)));
typedef _Float16 f16x8 __attribute__((ext_vector_type(8)));
typedef int      i32x4 __attribute__((ext_vector_type(4)));

namespace {
constexpr int B_ = 2, L_ = 2048, S_ = 2048, H_ = 16, E_ = 64;
constexpr int MBLK = 128;        // q rows per block (4 waves x 32)
constexpr int NT = 64;           // s-tile width
constexpr int NTILES = S_ / NT;  // 32

#define SCALE2f 0.1803368801111204f /* 0.125 * log2(e) */
#define MBIAS2f -1.8033688e8f       /* -1e9 * 0.125 * log2(e): exp2 -> exactly 0 */

// ws layout: [0,1MiB) mask bits | Kh f16 [b,h,s,e] 8.39MB | Vh f16 [b,h,e,s] 8.39MB
constexpr size_t KHOFF = (size_t)1 << 20;
constexpr size_t VHOFF = KHOFF + (size_t)B_ * H_ * S_ * E_ * 2;

__device__ __forceinline__ f16x2 cvt2(float a, float b) {
  return __builtin_bit_cast(f16x2, __builtin_amdgcn_cvt_pkrtz(a, b));
}
__device__ __forceinline__ int pkh(float a, float b) {
  return __builtin_bit_cast(int, __builtin_amdgcn_cvt_pkrtz(a, b));
}
union H8 { f16x8 v; i32x4 i; };
union H4 { f16x4 v; f16x2 h[2]; };

#define GLOAD_LDS16(g, l)                                              \
  __builtin_amdgcn_global_load_lds(                                    \
      (const __attribute__((address_space(1))) void*)(g),              \
      (__attribute__((address_space(3))) void*)(l), 16, 0, 0)
}  // namespace

// ---- pre-pass 1: mask fp32 -> 1 bit/element, u64 per (row, 64-s-chunk)
extern "C" __global__ __launch_bounds__(256)
void maskpack_kernel(const float* __restrict__ Mg, unsigned long long* __restrict__ Wb) {
  const int w    = (int)((blockIdx.x * 256 + threadIdx.x) >> 6);
  const int lane = threadIdx.x & 63;
  const float* src = Mg + (size_t)w * 2048 + lane;
  unsigned long long* dst = Wb + (size_t)w * 32;
#pragma unroll 8
  for (int j = 0; j < 32; ++j) {
    const unsigned long long bits = __ballot(src[j * 64] > 0.5f);
    if (lane == 0) dst[j] = bits;
  }
}

// ---- pre-pass 2: K [b,s,h,e] f32 -> Kh [b,h,s,e] f16 (h-gather, once)
extern "C" __global__ __launch_bounds__(256)
void kcvt_kernel(const float* __restrict__ Kg, _Float16* __restrict__ Kh) {
  const int idx = blockIdx.x * 256 + threadIdx.x;  // 8-e chunk id
  const int j = idx & 7;
  const int h = (idx >> 3) & (H_ - 1);
  const int s = (idx >> 7) & (S_ - 1);
  const int b = idx >> 18;
  const float* src = Kg + ((((size_t)b * S_ + s) * H_ + h) << 6) + j * 8;
  f32x4 x = *(const f32x4*)src, y = *(const f32x4*)(src + 4);
  i32x4 w = {pkh(x[0], x[1]), pkh(x[2], x[3]), pkh(y[0], y[1]), pkh(y[2], y[3])};
  *(i32x4*)(Kh + ((((size_t)b * H_ + h) * S_ + s) << 6) + j * 8) = w;
}

// ---- pre-pass 3: V [b,s,h,e] f32 -> Vh [b,h,e,s] f16 (transpose via LDS)
extern "C" __global__ __launch_bounds__(256)
void vcvt_kernel(const float* __restrict__ Vg, _Float16* __restrict__ Vh) {
  __shared__ _Float16 T[64][72];
  const int bid = blockIdx.x;  // (b,h,st)
  const int st = bid & 31;
  const int h  = (bid >> 5) & (H_ - 1);
  const int b  = bid >> 9;
  const int t  = threadIdx.x;
  const int sl = t >> 2;
  const int e0 = (t & 3) << 4;
  const float* src = Vg + ((((size_t)b * S_ + st * 64 + sl) * H_ + h) << 6) + e0;
#pragma unroll
  for (int i = 0; i < 4; ++i) {
    f32x4 x = *(const f32x4*)(src + i * 4);
#pragma unroll
    for (int c = 0; c < 4; ++c) T[e0 + i * 4 + c][sl] = (_Float16)x[c];
  }
  __syncthreads();
  const int er = t >> 2;
  const int s0 = (t & 3) << 4;
  _Float16* dst = Vh + (((((size_t)b * H_ + h) << 6) + er) * S_) + st * 64 + s0;
  *(i32x4*)dst       = *(const i32x4*)&T[er][s0];
  *(i32x4*)(dst + 8) = *(const i32x4*)&T[er][s0 + 8];
}

extern "C" __global__ __launch_bounds__(256, 2)
void fattn_kernel(const float* __restrict__ Qg, const _Float16* __restrict__ Kh,
                  const _Float16* __restrict__ Vh, const unsigned long long* __restrict__ Wb,
                  float* __restrict__ Og) {
  // unpadded (DMA dest is lane-contiguous); bank safety via XOR-granule swizzle
  __shared__ __align__(16) _Float16 Ks[2][NT][64];  // [s][e], 8 KB per buf
  __shared__ __align__(16) _Float16 Vt[2][E_][64];  // [e][s], 8 KB per buf

  const int tid  = threadIdx.x;
  const int wv   = tid >> 6;
  const int lane = tid & 63;
  const int qd   = lane >> 4;
  const int cl   = lane & 15;
  const int sw   = cl & 7;  // reader swizzle key (row & 7)

  // XCD-locality: bid%8 == bh%8 -> all 16 q-blocks of one (b,h) on one XCD
  const int bid = blockIdx.x;
  const int qb  = bid >> 5;
  const int bh  = bid & 31;
  const int h   = bh & (H_ - 1);
  const int b   = bh >> 4;

  const int l0 = qb * MBLK + wv * 32;

  // ---- Q fragments (B-operand of S^T = K Q^T), f16, from f32 global
  f16x8 qf[2][2];
#pragma unroll
  for (int mt = 0; mt < 2; ++mt) {
    const float* qp = Qg + ((((size_t)b * L_ + (l0 + mt * 16 + cl)) * H_ + h) << 6);
#pragma unroll
    for (int kb = 0; kb < 2; ++kb) {
      const int e0 = qd * 8 + kb * 32;
      f32x4 x = *(const f32x4*)(qp + e0);
      f32x4 y = *(const f32x4*)(qp + e0 + 4);
      H8 u;
      u.i = (i32x4){pkh(x[0], x[1]), pkh(x[2], x[3]), pkh(y[0], y[1]), pkh(y[2], y[3])};
      qf[mt][kb] = u.v;
    }
  }

  // ---- DMA lane constants: lane = 8*row_local + granule_slot
  const int rl  = lane >> 3;       // row within wave-iter (0..7)
  const int gsl = lane & 7;        // granule slot in LDS row
  const int gsw = gsl ^ rl;        // swizzled source granule (row&7 == rl)
  const _Float16* khb = Kh + ((((size_t)b * H_ + h) * S_) << 6);       // [s][e]
  const _Float16* vhb = Vh + ((((size_t)b * H_ + h) << 6) * (size_t)S_);  // [e][s]

  const unsigned long long* wbp = Wb + (((size_t)b * L_ + (l0 + cl)) << 5);

  // issue one tile's K+V staging via global_load_lds (16 B/lane, 2 wave-iters each)
  auto dma = [&](int buf, int t) {
#pragma unroll
    for (int p = 0; p < 2; ++p) {
      const int r0 = p * 32 + wv * 8;
      const _Float16* ksrc = khb + (((size_t)(t * 64 + r0 + rl)) << 6) + gsw * 8;
      GLOAD_LDS16(ksrc, &Ks[buf][r0][0]);
      const _Float16* vsrc = vhb + (size_t)(r0 + rl) * S_ + t * 64 + gsw * 8;
      GLOAD_LDS16(vsrc, &Vt[buf][r0][0]);
    }
  };

  const f32x4 zero4 = {0.f, 0.f, 0.f, 0.f};
  f32x4 acc[2][4];
#pragma unroll
  for (int mt = 0; mt < 2; ++mt)
#pragma unroll
    for (int et = 0; et < 4; ++et) acc[mt][et] = zero4;
  f32x4 rs4[2] = {zero4, zero4};

  dma(0, 0);
  unsigned long long mwcur = wbp[0];

  for (int t = 0; t < NTILES; ++t) {
    const int cb = t & 1;
    __syncthreads();  // drains DMA for buf[cb]; buf[cb^1] readers done

    if (t + 1 < NTILES) dma(cb ^ 1, t + 1);
    unsigned long long mwnext = 0;
    if (t + 1 < NTILES) mwnext = wbp[t + 1];

    // ---- S^T = K Q^T  (A: swizzled Ks rows b128; B: Q regs)
    f32x4 sc[4][2];
#pragma unroll
    for (int nt = 0; nt < 4; ++nt) {
      const _Float16* krow = &Ks[cb][nt * 16 + cl][0];
      const f16x8 a0 = *(const f16x8*)(krow + ((qd ^ sw) << 3));
      const f16x8 a1 = *(const f16x8*)(krow + (((qd + 4) ^ sw) << 3));
#pragma unroll
      for (int mt = 0; mt < 2; ++mt) {
        f32x4 c = zero4;
        c = __builtin_amdgcn_mfma_f32_16x16x32_f16(a0, qf[mt][0], c, 0, 0, 0);
        c = __builtin_amdgcn_mfma_f32_16x16x32_f16(a1, qf[mt][1], c, 0, 0, 0);
        sc[nt][mt] = c;  // q = mt*16+cl, s = nt*16 + qd*4 + r
      }
    }

    // ---- softmax numerator; P stays in registers as PV A-frags
    f16x4 pa[2][4];
    if (mwcur == ~0ull) {  // all-attend fast path
#pragma unroll
      for (int mt = 0; mt < 2; ++mt)
#pragma unroll
        for (int nt = 0; nt < 4; ++nt) {
          f32x4 p;
#pragma unroll
          for (int r = 0; r < 4; ++r)
            p[r] = __builtin_amdgcn_exp2f(sc[nt][mt][r] * SCALE2f);
          rs4[mt] += p;
          H4 u;
          u.h[0] = cvt2(p[0], p[1]);
          u.h[1] = cvt2(p[2], p[3]);
          pa[mt][nt] = u.v;
        }
    } else {
      const unsigned lo = (unsigned)mwcur;
      const unsigned hi = (unsigned)(mwcur >> 32);
#pragma unroll
      for (int mt = 0; mt < 2; ++mt)
#pragma unroll
        for (int nt = 0; nt < 4; ++nt) {
          const unsigned shm = ((nt < 2) ? lo : hi) >> ((nt & 1) * 16 + qd * 4);
          f32x4 p;
#pragma unroll
          for (int r = 0; r < 4; ++r) {
            const float bias = (shm & (1u << r)) ? 0.f : MBIAS2f;
            p[r] = __builtin_amdgcn_exp2f(__builtin_fmaf(sc[nt][mt][r], SCALE2f, bias));
          }
          rs4[mt] += p;
          H4 u;
          u.h[0] = cvt2(p[0], p[1]);
          u.h[1] = cvt2(p[2], p[3]);
          pa[mt][nt] = u.v;
        }
    }

    // ---- O += P V  (A: P regs; B: swizzled Vt rows b64)
#pragma unroll
    for (int nt = 0; nt < 4; ++nt)
#pragma unroll
      for (int et = 0; et < 4; ++et) {
        const _Float16* vrow = &Vt[cb][et * 16 + cl][0];
        const f16x4 bv = *(const f16x4*)(vrow + ((((2 * nt + (qd >> 1)) ^ sw) << 3) + ((qd & 1) << 2)));
        acc[0][et] = __builtin_amdgcn_mfma_f32_16x16x16f16(pa[0][nt], bv, acc[0][et], 0, 0, 0);
        acc[1][et] = __builtin_amdgcn_mfma_f32_16x16x16f16(pa[1][nt], bv, acc[1][et], 0, 0, 0);
      }

    mwcur = mwnext;
  }

  // ---- epilogue: row-sum reduce, broadcast inv per q-row, store
#pragma unroll
  for (int mt = 0; mt < 2; ++mt) {
    float v = rs4[mt][0] + rs4[mt][1] + rs4[mt][2] + rs4[mt][3];
    v += __shfl_xor(v, 16, 64);
    v += __shfl_xor(v, 32, 64);  // every lane: sum for q = mt*16 + cl
#pragma unroll
    for (int r = 0; r < 4; ++r) {
      const float invq = 1.0f / __shfl(v, qd * 4 + r, 64);
      const int l = l0 + mt * 16 + qd * 4 + r;
      float* op = Og + ((((size_t)b * H_ + h) * L_ + l) << 6) + cl;
#pragma unroll
      for (int et = 0; et < 4; ++et) op[et * 16] = acc[mt][et][r] * invq;
    }
  }
}

extern "C" void kernel_launch(void* const* d_in, const int* in_sizes, int n_in,
                              void* d_out, int out_size, void* d_ws, size_t ws_size,
                              hipStream_t stream) {
  const float* Q = (const float*)d_in[0];
  const float* K = (const float*)d_in[1];
  const float* V = (const float*)d_in[2];
  const float* M = (const float*)d_in[3];
  float* O = (float*)d_out;
  unsigned long long* Wb = (unsigned long long*)d_ws;              // 1 MiB
  _Float16* Khp = (_Float16*)((char*)d_ws + KHOFF);                // 8.39 MB
  _Float16* Vhp = (_Float16*)((char*)d_ws + VHOFF);                // 8.39 MB

  hipLaunchKernelGGL(maskpack_kernel, dim3(B_ * L_ / 4), dim3(256), 0, stream, M, Wb);
  hipLaunchKernelGGL(kcvt_kernel, dim3(B_ * S_ * H_ * 8 / 256), dim3(256), 0, stream, K, Khp);
  hipLaunchKernelGGL(vcvt_kernel, dim3(B_ * H_ * (S_ / 64)), dim3(256), 0, stream, V, Vhp);
  hipLaunchKernelGGL(fattn_kernel, dim3(B_ * H_ * (L_ / MBLK)), dim3(256), 0, stream,
                     Q, Khp, Vhp, Wb, O);
}